// Round 7
// baseline (301.982 us; speedup 1.0000x reference)
//
#include <hip/hip_runtime.h>
#include <hip/hip_bf16.h>
#include <stdint.h>

typedef __attribute__((ext_vector_type(8))) short short8;
typedef __attribute__((ext_vector_type(4))) short short4_t;
typedef __attribute__((ext_vector_type(4))) float f32x4;
typedef __attribute__((ext_vector_type(2))) unsigned int u32x2;
typedef __attribute__((ext_vector_type(4))) unsigned int u32x4;

union FragU { u32x4 u; short8 s; };
union Frag2U { u32x2 u; short4_t s; };

__device__ __forceinline__ unsigned short f2bf(float f) {
  union { float f; uint32_t u; } v; v.f = f;
  uint32_t u = v.u;
  return (unsigned short)((u + 0x7FFFu + ((u >> 16) & 1u)) >> 16);
}

__device__ __forceinline__ unsigned pk2(float a, float b) {
  return (unsigned)f2bf(a) | ((unsigned)f2bf(b) << 16);
}

#if defined(__has_builtin)
#if __has_builtin(__builtin_amdgcn_mfma_f32_16x16x16bf16_1k)
#define HAVE_MFMA16_BUILTIN 1
#endif
#if __has_builtin(__builtin_amdgcn_exp2f)
#define HAVE_EXP2_BUILTIN 1
#endif
#endif

__device__ __forceinline__ float fexp2(float x) {
#ifdef HAVE_EXP2_BUILTIN
  return __builtin_amdgcn_exp2f(x);
#else
  return exp2f(x);
#endif
}

__device__ __forceinline__ f32x4 mfma16(u32x2 a, u32x2 b, f32x4 c) {
#ifdef HAVE_MFMA16_BUILTIN
  Frag2U ua, ub;
  ua.u = a; ub.u = b;
  return __builtin_amdgcn_mfma_f32_16x16x16bf16_1k(ua.s, ub.s, c, 0, 0, 0);
#else
  asm volatile("s_nop 1\n\t"
               "v_mfma_f32_16x16x16_bf16 %0, %1, %2, %0\n\t"
               "s_nop 7\n\t"
               "s_nop 7"
               : "+v"(c) : "v"(a), "v"(b));
  return c;
#endif
}

// ---------------- K0: convert W (f32, [n][k] row-major) -> bf16, same layout ----------------
__global__ __launch_bounds__(256) void k_wconv(const float* __restrict__ WQ,
                                               const float* __restrict__ WK,
                                               const float* __restrict__ WV,
                                               unsigned short* __restrict__ Wbf) {
  int mat = blockIdx.x >> 5;
  int i = blockIdx.x & 31;
  const float* W = (mat == 0) ? WQ : ((mat == 1) ? WK : WV);
  int off = i * 2048 + threadIdx.x * 8;
  f32x4 v0 = *(const f32x4*)(W + off), v1 = *(const f32x4*)(W + off + 4);
  u32x4 pk;
  pk.x = pk2(v0.x, v0.y); pk.y = pk2(v0.z, v0.w);
  pk.z = pk2(v1.x, v1.y); pk.w = pk2(v1.z, v1.w);
  *(u32x4*)(Wbf + (size_t)mat * 65536 + off) = pk;
}

// ---------------- K1a: per-column partial sums over 64-row chunks ----------------
__global__ __launch_bounds__(256) void k_stats(const float* __restrict__ x,
                                               float* __restrict__ psum,
                                               float* __restrict__ psq) {
  int t = threadIdx.x;
  int cb = blockIdx.x & 3;
  int ck = blockIdx.x >> 2;
  int c0 = cb * 1024 + t * 4;
  f32x4 s = {0.f, 0.f, 0.f, 0.f}, q = {0.f, 0.f, 0.f, 0.f};
  const float* base = x + (size_t)ck * 64 * 4096 + c0;
#pragma unroll 4
  for (int r = 0; r < 64; ++r) {
    f32x4 v = *(const f32x4*)(base + (size_t)r * 4096);
    s += v;
    q += v * v;
  }
  *(f32x4*)(psum + (size_t)ck * 4096 + c0) = s;
  *(f32x4*)(psq + (size_t)ck * 4096 + c0) = q;
}

// ---------------- K1b: finalize BN -> fused scale/shift coeffs ----------------
__global__ __launch_bounds__(256) void k_finalize(const float* __restrict__ psum,
                                                  const float* __restrict__ psq,
                                                  const float* __restrict__ gamma,
                                                  const float* __restrict__ beta,
                                                  float* __restrict__ An,
                                                  float* __restrict__ Bn) {
  int c = blockIdx.x * 256 + threadIdx.x;
  float s = 0.f, q = 0.f;
  for (int k = 0; k < 64; ++k) {
    s += psum[k * 4096 + c];
    q += psq[k * 4096 + c];
  }
  float mean = s * (1.0f / 4096.0f);
  float var = q * (1.0f / 4096.0f) - mean * mean;
  float a = gamma[c] * rsqrtf(var + 1e-5f);
  An[c] = a;
  Bn[c] = beta[c] - mean * a;
}

// ---------------- K2: fully-fused QKV + attention; one wave = one batch row ----------------
// No LDS, no barriers. All fragments live in registers:
//   af[kk]  : Xn[p=lr][dd=kk*32+g*8+j]    (MFMA32 A-frag for Q/K, B-frag for V)
//   Q GEMM  : A=af(m=p), B=WQ^T(n=e)  -> C[p=g*4+rg][e=nt*16+lr] -> qf[nt] (mfma16 B-frag)
//   K GEMM  : same                    -> kf[nt] (mfma16 A-frag)
//   V GEMM  : A=WV(m=f), B=af(n=p)    -> C[f=mt*16+g*4+rg][p=lr] -> vf[mt] (mfma16 A-frag)
//   QK^T    : st = mfma16(kf[c2], qf[nt]) = S^T[f][e]; P = exp2(st) (log2e/16 folded into Q)
//   PV      : accT[nt] += mfma16(vf[c2], pB)  -> C[p][e]
__global__ __launch_bounds__(256, 2) void k_fused(
    const float* __restrict__ x, const float* __restrict__ An, const float* __restrict__ Bn,
    const unsigned short* __restrict__ Wbf,
    const float* __restrict__ bQ, const float* __restrict__ bK, const float* __restrict__ bV,
    float* __restrict__ out) {
  int t = threadIdx.x;
  int w = t >> 6, ln = t & 63, lr = ln & 15, g = ln >> 4;
  int b = blockIdx.x * 4 + w;
  const float* xrow = x + (size_t)b * 4096;

  f32x4 z4 = {0.f, 0.f, 0.f, 0.f};

  // ---- build af[8] (normalized Xn fragments) ----
  FragU af[8];
#pragma unroll
  for (int kk = 0; kk < 8; ++kk) {
    int dd = kk * 32 + g * 8;
    int c = lr * 256 + dd;
    f32x4 v0 = *(const f32x4*)(xrow + c), v1 = *(const f32x4*)(xrow + c + 4);
    f32x4 a0 = *(const f32x4*)(An + c), a1 = *(const f32x4*)(An + c + 4);
    f32x4 b0 = *(const f32x4*)(Bn + c), b1 = *(const f32x4*)(Bn + c + 4);
    f32x4 n0 = v0 * a0 + b0, n1 = v1 * a1 + b1;
    af[kk].u.x = pk2(n0.x, n0.y);
    af[kk].u.y = pk2(n0.z, n0.w);
    af[kk].u.z = pk2(n1.x, n1.y);
    af[kk].u.w = pk2(n1.z, n1.w);
  }

  const char* WQp = (const char*)Wbf;
  const char* WKp = (const char*)(Wbf + 65536);
  const char* WVp = (const char*)(Wbf + 131072);

  // ---- Q GEMM -> qf (with bias, 1/16 and log2e folded) ----
  u32x2 qf[16];
  {
    f32x4 acc[16];
#pragma unroll
    for (int nt = 0; nt < 16; ++nt) acc[nt] = z4;
#pragma unroll
    for (int kk = 0; kk < 8; ++kk) {
#pragma unroll
      for (int nt = 0; nt < 16; ++nt) {
        FragU bfr;
        bfr.u = *(const u32x4*)(WQp + (size_t)(nt * 16 + lr) * 512 + kk * 64 + g * 16);
        acc[nt] = __builtin_amdgcn_mfma_f32_16x16x32_bf16(af[kk].s, bfr.s, acc[nt], 0, 0, 0);
      }
    }
    const float QS = 0.0625f * 1.44269504088896f;
#pragma unroll
    for (int nt = 0; nt < 16; ++nt) {
      float bq = bQ[nt * 16 + lr];
      qf[nt].x = pk2((acc[nt][0] + bq) * QS, (acc[nt][1] + bq) * QS);
      qf[nt].y = pk2((acc[nt][2] + bq) * QS, (acc[nt][3] + bq) * QS);
    }
  }

  // ---- K GEMM -> kf ----
  u32x2 kf[16];
  {
    f32x4 acc[16];
#pragma unroll
    for (int nt = 0; nt < 16; ++nt) acc[nt] = z4;
#pragma unroll
    for (int kk = 0; kk < 8; ++kk) {
#pragma unroll
      for (int nt = 0; nt < 16; ++nt) {
        FragU bfr;
        bfr.u = *(const u32x4*)(WKp + (size_t)(nt * 16 + lr) * 512 + kk * 64 + g * 16);
        acc[nt] = __builtin_amdgcn_mfma_f32_16x16x32_bf16(af[kk].s, bfr.s, acc[nt], 0, 0, 0);
      }
    }
#pragma unroll
    for (int nt = 0; nt < 16; ++nt) {
      float bk = bK[nt * 16 + lr];
      kf[nt].x = pk2(acc[nt][0] + bk, acc[nt][1] + bk);
      kf[nt].y = pk2(acc[nt][2] + bk, acc[nt][3] + bk);
    }
  }

  // ---- V GEMM (swapped: A=WV rows f, B=af) -> vf ----
  u32x2 vf[16];
  {
    f32x4 acc[16];
#pragma unroll
    for (int mt = 0; mt < 16; ++mt) acc[mt] = z4;
#pragma unroll
    for (int kk = 0; kk < 8; ++kk) {
#pragma unroll
      for (int mt = 0; mt < 16; ++mt) {
        FragU wf;
        wf.u = *(const u32x4*)(WVp + (size_t)(mt * 16 + lr) * 512 + kk * 64 + g * 16);
        acc[mt] = __builtin_amdgcn_mfma_f32_16x16x32_bf16(wf.s, af[kk].s, acc[mt], 0, 0, 0);
      }
    }
#pragma unroll
    for (int mt = 0; mt < 16; ++mt) {
      int f0 = mt * 16 + g * 4;
      f32x4 bv4 = *(const f32x4*)(bV + f0);
      vf[mt].x = pk2(acc[mt][0] + bv4.x, acc[mt][1] + bv4.y);
      vf[mt].y = pk2(acc[mt][2] + bv4.z, acc[mt][3] + bv4.w);
    }
  }

  // ---- attention: S^T chunks -> exp2 -> PV, all in registers ----
  f32x4 accT[16];
  float denp[16];
#pragma unroll
  for (int nt = 0; nt < 16; ++nt) { accT[nt] = z4; denp[nt] = 0.f; }

#pragma unroll
  for (int c2 = 0; c2 < 16; ++c2) {
#pragma unroll
    for (int nt = 0; nt < 16; ++nt) {
      f32x4 st = mfma16(kf[c2], qf[nt], z4);
      float p0 = fexp2(st[0]);
      float p1 = fexp2(st[1]);
      float p2 = fexp2(st[2]);
      float p3 = fexp2(st[3]);
      denp[nt] += (p0 + p1) + (p2 + p3);
      u32x2 pB;
      pB.x = pk2(p0, p1);
      pB.y = pk2(p2, p3);
      accT[nt] = mfma16(vf[c2], pB, accT[nt]);
    }
  }

  // ---- den reduce over g-groups; epilogue ----
  size_t rowbase = (size_t)b * 4096;
#pragma unroll
  for (int nt = 0; nt < 16; ++nt) {
    float v = denp[nt];
    v += __shfl_xor(v, 16);
    v += __shfl_xor(v, 32);
    float inv = 1.0f / v;
    size_t col = (size_t)(nt * 16 + lr) * 16 + g * 4;
    f32x4 xr = *(const f32x4*)(x + rowbase + col);
    f32x4 o = accT[nt] * inv + xr;
    *(f32x4*)(out + rowbase + col) = o;
  }
}

extern "C" void kernel_launch(void* const* d_in, const int* in_sizes, int n_in,
                              void* d_out, int out_size, void* d_ws, size_t ws_size,
                              hipStream_t stream) {
  const float* x = (const float*)d_in[0];
  const float* WQ = (const float*)d_in[1];
  const float* bQ = (const float*)d_in[2];
  const float* WK = (const float*)d_in[3];
  const float* bK = (const float*)d_in[4];
  const float* WV = (const float*)d_in[5];
  const float* bV = (const float*)d_in[6];
  const float* gamma = (const float*)d_in[7];
  const float* beta = (const float*)d_in[8];
  float* out = (float*)d_out;
  char* ws = (char*)d_ws;

  float* psum = (float*)(ws);                               // 1 MB
  float* psq = (float*)(ws + (1 << 20));                    // 1 MB
  float* An = (float*)(ws + (2 << 20));                     // 16 KB
  float* Bn = (float*)(ws + (2 << 20) + (16 << 10));        // 16 KB
  unsigned short* Wbf = (unsigned short*)(ws + (3 << 20));  // 384 KB

  hipLaunchKernelGGL(k_wconv, dim3(96), dim3(256), 0, stream, WQ, WK, WV, Wbf);
  hipLaunchKernelGGL(k_stats, dim3(256), dim3(256), 0, stream, x, psum, psq);
  hipLaunchKernelGGL(k_finalize, dim3(16), dim3(256), 0, stream, psum, psq, gamma, beta, An, Bn);
  hipLaunchKernelGGL(k_fused, dim3(1024), dim3(256), 0, stream, x, An, Bn,
                     Wbf, bQ, bK, bV, out);
}

// Round 9
// 268.907 us; speedup vs baseline: 1.1230x; 1.1230x over previous
//
#include <hip/hip_runtime.h>
#include <hip/hip_bf16.h>
#include <stdint.h>

typedef __attribute__((ext_vector_type(8))) short short8;
typedef __attribute__((ext_vector_type(4))) short short4_t;
typedef __attribute__((ext_vector_type(4))) float f32x4;
typedef __attribute__((ext_vector_type(2))) unsigned int u32x2;
typedef __attribute__((ext_vector_type(4))) unsigned int u32x4;

union FragU { u32x4 u; short8 s; };
union Frag2U { u32x2 u; short4_t s; };

__device__ __forceinline__ unsigned short f2bf(float f) {
  union { float f; uint32_t u; } v; v.f = f;
  uint32_t u = v.u;
  return (unsigned short)((u + 0x7FFFu + ((u >> 16) & 1u)) >> 16);
}

__device__ __forceinline__ unsigned pk2(float a, float b) {
  return (unsigned)f2bf(a) | ((unsigned)f2bf(b) << 16);
}

#if defined(__has_builtin)
#if __has_builtin(__builtin_amdgcn_mfma_f32_16x16x16bf16_1k)
#define HAVE_MFMA16_BUILTIN 1
#endif
#if __has_builtin(__builtin_amdgcn_exp2f)
#define HAVE_EXP2_BUILTIN 1
#endif
#endif

__device__ __forceinline__ float fexp2(float x) {
#ifdef HAVE_EXP2_BUILTIN
  return __builtin_amdgcn_exp2f(x);
#else
  return exp2f(x);
#endif
}

__device__ __forceinline__ f32x4 mfma16(u32x2 a, u32x2 b, f32x4 c) {
#ifdef HAVE_MFMA16_BUILTIN
  Frag2U ua, ub;
  ua.u = a; ub.u = b;
  return __builtin_amdgcn_mfma_f32_16x16x16bf16_1k(ua.s, ub.s, c, 0, 0, 0);
#else
  asm volatile("s_nop 1\n\t"
               "v_mfma_f32_16x16x16_bf16 %0, %1, %2, %0\n\t"
               "s_nop 7\n\t"
               "s_nop 7"
               : "+v"(c) : "v"(a), "v"(b));
  return c;
#endif
}

// ---------------- K0: convert W (f32, [n][k] row-major) -> bf16, same layout ----------------
__global__ __launch_bounds__(256) void k_wconv(const float* __restrict__ WQ,
                                               const float* __restrict__ WK,
                                               const float* __restrict__ WV,
                                               unsigned short* __restrict__ Wbf) {
  int mat = blockIdx.x >> 5;
  int i = blockIdx.x & 31;
  const float* W = (mat == 0) ? WQ : ((mat == 1) ? WK : WV);
  int off = i * 2048 + threadIdx.x * 8;
  f32x4 v0 = *(const f32x4*)(W + off), v1 = *(const f32x4*)(W + off + 4);
  u32x4 pk;
  pk.x = pk2(v0.x, v0.y); pk.y = pk2(v0.z, v0.w);
  pk.z = pk2(v1.x, v1.y); pk.w = pk2(v1.z, v1.w);
  *(u32x4*)(Wbf + (size_t)mat * 65536 + off) = pk;
}

// ---------------- K1a: per-column partial sums over 64-row chunks ----------------
__global__ __launch_bounds__(256) void k_stats(const float* __restrict__ x,
                                               float* __restrict__ psum,
                                               float* __restrict__ psq) {
  int t = threadIdx.x;
  int cb = blockIdx.x & 3;
  int ck = blockIdx.x >> 2;
  int c0 = cb * 1024 + t * 4;
  f32x4 s = {0.f, 0.f, 0.f, 0.f}, q = {0.f, 0.f, 0.f, 0.f};
  const float* base = x + (size_t)ck * 64 * 4096 + c0;
#pragma unroll 4
  for (int r = 0; r < 64; ++r) {
    f32x4 v = *(const f32x4*)(base + (size_t)r * 4096);
    s += v;
    q += v * v;
  }
  *(f32x4*)(psum + (size_t)ck * 4096 + c0) = s;
  *(f32x4*)(psq + (size_t)ck * 4096 + c0) = q;
}

// ---------------- K1b: finalize BN -> fused scale/shift coeffs ----------------
__global__ __launch_bounds__(256) void k_finalize(const float* __restrict__ psum,
                                                  const float* __restrict__ psq,
                                                  const float* __restrict__ gamma,
                                                  const float* __restrict__ beta,
                                                  float* __restrict__ An,
                                                  float* __restrict__ Bn) {
  int c = blockIdx.x * 256 + threadIdx.x;
  float s = 0.f, q = 0.f;
  for (int k = 0; k < 64; ++k) {
    s += psum[k * 4096 + c];
    q += psq[k * 4096 + c];
  }
  float mean = s * (1.0f / 4096.0f);
  float var = q * (1.0f / 4096.0f) - mean * mean;
  float a = gamma[c] * rsqrtf(var + 1e-5f);
  An[c] = a;
  Bn[c] = beta[c] - mean * a;
}

// ---------------- K2: fused QKV + attention, K/V streamed per 16-col chunk ----------------
// One wave = one batch row. Persistent regs: af[8](32) + qf[16](32) + accT[16](64) + denp(16).
// Per c2 chunk: kf/vf computed on the fly from af (16 MFMA32), then 16x(QK^T, exp2, PV).
__global__ __launch_bounds__(256, 2) void k_fused(
    const float* __restrict__ x, const float* __restrict__ An, const float* __restrict__ Bn,
    const unsigned short* __restrict__ Wbf,
    const float* __restrict__ bQ, const float* __restrict__ bK, const float* __restrict__ bV,
    float* __restrict__ out) {
  int t = threadIdx.x;
  int w = t >> 6, ln = t & 63, lr = ln & 15, g = ln >> 4;
  int b = blockIdx.x * 4 + w;
  const float* xrow = x + (size_t)b * 4096;

  f32x4 z4 = {0.f, 0.f, 0.f, 0.f};

  // ---- build af[8]: Xn[p=lr][dd=kk*32+g*8+j] (A-frag for Q/K GEMM, B-frag for V GEMM) ----
  FragU af[8];
#pragma unroll
  for (int kk = 0; kk < 8; ++kk) {
    int c = lr * 256 + kk * 32 + g * 8;
    f32x4 v0 = *(const f32x4*)(xrow + c), v1 = *(const f32x4*)(xrow + c + 4);
    f32x4 a0 = *(const f32x4*)(An + c), a1 = *(const f32x4*)(An + c + 4);
    f32x4 b0 = *(const f32x4*)(Bn + c), b1 = *(const f32x4*)(Bn + c + 4);
    f32x4 n0 = v0 * a0 + b0, n1 = v1 * a1 + b1;
    af[kk].u.x = pk2(n0.x, n0.y);
    af[kk].u.y = pk2(n0.z, n0.w);
    af[kk].u.z = pk2(n1.x, n1.y);
    af[kk].u.w = pk2(n1.z, n1.w);
  }

  const char* WQp = (const char*)Wbf;
  const char* WKp = (const char*)(Wbf + 65536);
  const char* WVp = (const char*)(Wbf + 131072);

  // ---- Q GEMM -> qf[16]: C[p=g*4+rg][e=nt*16+lr] packed as mfma16 B-frag ----
  u32x2 qf[16];
  {
    f32x4 acc[16];
#pragma unroll
    for (int nt = 0; nt < 16; ++nt) acc[nt] = z4;
#pragma unroll
    for (int kk = 0; kk < 8; ++kk) {
#pragma unroll
      for (int nt = 0; nt < 16; ++nt) {
        FragU bfr;
        bfr.u = *(const u32x4*)(WQp + (size_t)(nt * 16 + lr) * 512 + kk * 64 + g * 16);
        acc[nt] = __builtin_amdgcn_mfma_f32_16x16x32_bf16(af[kk].s, bfr.s, acc[nt], 0, 0, 0);
      }
    }
    const float QS = 0.0625f * 1.44269504088896f;  // 1/sqrt(d) * log2(e)
#pragma unroll
    for (int nt = 0; nt < 16; ++nt) {
      float bq = bQ[nt * 16 + lr];
      qf[nt].x = pk2((acc[nt][0] + bq) * QS, (acc[nt][1] + bq) * QS);
      qf[nt].y = pk2((acc[nt][2] + bq) * QS, (acc[nt][3] + bq) * QS);
    }
  }

  // ---- attention with streamed K/V chunks ----
  f32x4 accT[16];
  float denp[16];
#pragma unroll
  for (int nt = 0; nt < 16; ++nt) { accT[nt] = z4; denp[nt] = 0.f; }

  const char* wkbase = WKp + (size_t)lr * 512 + g * 16;
  const char* wvbase = WVp + (size_t)lr * 512 + g * 16;

  for (int c2 = 0; c2 < 16; ++c2) {
    const char* wk = wkbase + c2 * 8192;
    const char* wv = wvbase + c2 * 8192;

    // K chunk GEMM: C[p][f=c2*16+lr]; V chunk GEMM (swapped): C[f=c2*16+g*4+rg][p=lr]
    f32x4 ka0 = z4, ka1 = z4, va0 = z4, va1 = z4;
#pragma unroll
    for (int kk = 0; kk < 8; kk += 2) {
      FragU k0, k1, v0, v1;
      k0.u = *(const u32x4*)(wk + kk * 64);
      k1.u = *(const u32x4*)(wk + kk * 64 + 64);
      v0.u = *(const u32x4*)(wv + kk * 64);
      v1.u = *(const u32x4*)(wv + kk * 64 + 64);
      ka0 = __builtin_amdgcn_mfma_f32_16x16x32_bf16(af[kk].s, k0.s, ka0, 0, 0, 0);
      ka1 = __builtin_amdgcn_mfma_f32_16x16x32_bf16(af[kk + 1].s, k1.s, ka1, 0, 0, 0);
      va0 = __builtin_amdgcn_mfma_f32_16x16x32_bf16(v0.s, af[kk].s, va0, 0, 0, 0);
      va1 = __builtin_amdgcn_mfma_f32_16x16x32_bf16(v1.s, af[kk + 1].s, va1, 0, 0, 0);
    }
    f32x4 ka = ka0 + ka1;
    f32x4 va = va0 + va1;

    float bk = bK[c2 * 16 + lr];
    f32x4 bv4 = *(const f32x4*)(bV + c2 * 16 + g * 4);

    u32x2 kf, vf;
    kf.x = pk2(ka[0] + bk, ka[1] + bk);
    kf.y = pk2(ka[2] + bk, ka[3] + bk);
    vf.x = pk2(va[0] + bv4.x, va[1] + bv4.y);
    vf.y = pk2(va[2] + bv4.z, va[3] + bv4.w);

    // QK^T chunk -> exp2 -> PV
#pragma unroll
    for (int nt = 0; nt < 16; ++nt) {
      f32x4 st = mfma16(kf, qf[nt], z4);
      float p0 = fexp2(st[0]);
      float p1 = fexp2(st[1]);
      float p2 = fexp2(st[2]);
      float p3 = fexp2(st[3]);
      denp[nt] += (p0 + p1) + (p2 + p3);
      u32x2 pB;
      pB.x = pk2(p0, p1);
      pB.y = pk2(p2, p3);
      accT[nt] = mfma16(vf, pB, accT[nt]);
    }
  }

  // ---- den reduce over g-groups; epilogue: accT[nt][rg] = acc^T[p=g*4+rg][e=nt*16+lr] ----
  size_t rowbase = (size_t)b * 4096;
#pragma unroll
  for (int nt = 0; nt < 16; ++nt) {
    float v = denp[nt];
    v += __shfl_xor(v, 16);
    v += __shfl_xor(v, 32);
    float inv = 1.0f / v;
    size_t col = (size_t)(nt * 16 + lr) * 16 + g * 4;
    f32x4 xr = *(const f32x4*)(x + rowbase + col);
    f32x4 o = accT[nt] * inv + xr;
    *(f32x4*)(out + rowbase + col) = o;
  }
}

extern "C" void kernel_launch(void* const* d_in, const int* in_sizes, int n_in,
                              void* d_out, int out_size, void* d_ws, size_t ws_size,
                              hipStream_t stream) {
  const float* x = (const float*)d_in[0];
  const float* WQ = (const float*)d_in[1];
  const float* bQ = (const float*)d_in[2];
  const float* WK = (const float*)d_in[3];
  const float* bK = (const float*)d_in[4];
  const float* WV = (const float*)d_in[5];
  const float* bV = (const float*)d_in[6];
  const float* gamma = (const float*)d_in[7];
  const float* beta = (const float*)d_in[8];
  float* out = (float*)d_out;
  char* ws = (char*)d_ws;

  float* psum = (float*)(ws);                               // 1 MB
  float* psq = (float*)(ws + (1 << 20));                    // 1 MB
  float* An = (float*)(ws + (2 << 20));                     // 16 KB
  float* Bn = (float*)(ws + (2 << 20) + (16 << 10));        // 16 KB
  unsigned short* Wbf = (unsigned short*)(ws + (3 << 20));  // 384 KB

  hipLaunchKernelGGL(k_wconv, dim3(96), dim3(256), 0, stream, WQ, WK, WV, Wbf);
  hipLaunchKernelGGL(k_stats, dim3(256), dim3(256), 0, stream, x, psum, psq);
  hipLaunchKernelGGL(k_finalize, dim3(16), dim3(256), 0, stream, psum, psq, gamma, beta, An, Bn);
  hipLaunchKernelGGL(k_fused, dim3(1024), dim3(256), 0, stream, x, An, Bn,
                     Wbf, bQ, bK, bV, out);
}